// Round 1
// 281.424 us; speedup vs baseline: 1.1576x; 1.1576x over previous
//
#include <hip/hip_runtime.h>

// SmoothGCN: out = ((x@Wn + bn) + (segsum(x[src]*w, dst)@We + be)) @ Wm + bm
// Refactor: y = x@We; h = x@Wn + bn + be; h[dst] += w_e*y[src]; out = h@Wm + bm
// R7: binA was 85us with VALU 0.8% / HBM 11% / Mfma 0 -- 1.6M global
// atomic-with-return round trips + 1.6M scattered 8B stores (67MB writeback
// for a 12.8MB payload). binC replaces it with an LDS counting sort per
// 4096-edge block: LDS-atomic ranks, ONE global atomicAdd per (block,bin)
// to reserve space (~0.57M atomics, 4 independent per thread), then
// bin-grouped coalesced write-out. Within-bin order is free (gatherB
// re-sorts by node), so no cross-block prefix passes are needed.

constexpr int N_NODES  = 50000;
constexpr int N_EDGES  = 1600000;
constexpr int IN_FEAT  = 256;
constexpr int HID      = 128;
constexpr int OUT_FEAT = 256;

constexpr int BIN_SZ   = 32;                                // nodes per bin
constexpr int N_BINS   = (N_NODES + BIN_SZ - 1) / BIN_SZ;   // 1563
constexpr int CAPBIN   = 1536;   // mean 1024, multinomial max ~1150, P(>1536)~0
constexpr int EPB      = 4096;   // edges per binC block
constexpr int N_CBLK   = (N_EDGES + EPB - 1) / EPB;         // 391

typedef __attribute__((ext_vector_type(8))) short bf16x8;
typedef __attribute__((ext_vector_type(4))) float f32x4;

static __device__ __forceinline__ unsigned short f2bf(float f) {
    unsigned u = __builtin_bit_cast(unsigned, f);
    u += 0x7FFF + ((u >> 16) & 1);          // round-to-nearest-even
    return (unsigned short)(u >> 16);
}
static __device__ __forceinline__ float bflo(unsigned u) {
    return __builtin_bit_cast(float, u << 16);
}
static __device__ __forceinline__ float bfhi(unsigned u) {
    return __builtin_bit_cast(float, u & 0xFFFF0000u);
}

// ---------------- k0: transpose+convert weights to bf16 ----------------
__global__ __launch_bounds__(256) void k0_convert(
    const float* __restrict__ Wn, const float* __restrict__ We,
    const float* __restrict__ Wm,
    unsigned short* __restrict__ Wcat_t, unsigned short* __restrict__ Wmt)
{
    int n = blockIdx.x;      // 0..255
    int k = threadIdx.x;     // 0..255
    float v = (n < HID) ? Wn[(size_t)k * HID + n] : We[(size_t)k * HID + (n - HID)];
    Wcat_t[(size_t)n * IN_FEAT + k] = f2bf(v);
    if (k < HID) Wmt[(size_t)n * HID + k] = f2bf(Wm[(size_t)k * OUT_FEAT + n]);
}

// ---------------- binC: LDS counting sort of edges into dst bins ----------
// Per block: 4096 edges. Phase 1: LDS histogram over 1563 bins (LDS atomics
// return within-(block,bin) rank). Phase 2: block scan of hist -> local
// offsets (in place) + one global atomicAdd per nonzero bin to reserve a
// contiguous range in that bin's entries region. Phase 3: scatter to LDS in
// bin-sorted order. Phase 4: write out -- consecutive lanes hit consecutive
// sorted slots, so each bin's ~2.6 entries go out as one grouped segment.
// meta carries the bin in bits 31:21 only inside LDS; stripped on write.
__global__ __launch_bounds__(512) void binC(
    const int* __restrict__ src, const int* __restrict__ dst,
    const float* __restrict__ w, int* __restrict__ cursor,
    int2* __restrict__ entries)
{
    __shared__ int  hist[N_BINS];    // counts, then (in place) local excl offsets
    __shared__ int  gbase[N_BINS];   // reserved global base per bin
    __shared__ int  wsum[8];
    __shared__ int  stot;
    __shared__ int2 sorted[EPB];     // 32 KB

    const int t = threadIdx.x;
    const int wave = t >> 6, lane = t & 63;
    const int e0 = blockIdx.x * EPB;

    for (int i = t; i < N_BINS; i += 512) hist[i] = 0;
    __syncthreads();

    // load my 8 edges (coalesced), rank within (block,bin) via LDS atomics
    int meta[8], wb[8], rk[8], bn[8];
    #pragma unroll
    for (int k = 0; k < 8; ++k) {
        int e = e0 + t + k * 512;
        bn[k] = -1;
        if (e < N_EDGES) {
            int d = dst[e];
            int b = d >> 5;
            bn[k]   = b;
            meta[k] = src[e] | ((d & 31) << 16) | (b << 21);  // src<65536 ok
            wb[k]   = __float_as_int(w[e]);
            rk[k]   = atomicAdd(&hist[b], 1);
        }
    }
    __syncthreads();

    // block exclusive scan of hist (4 contiguous bins per thread)
    const int b4 = t * 4;
    int c0 = 0, c1 = 0, c2 = 0, c3 = 0;
    if (b4 + 0 < N_BINS) c0 = hist[b4 + 0];
    if (b4 + 1 < N_BINS) c1 = hist[b4 + 1];
    if (b4 + 2 < N_BINS) c2 = hist[b4 + 2];
    if (b4 + 3 < N_BINS) c3 = hist[b4 + 3];
    const int s = c0 + c1 + c2 + c3;
    int pre = s;
    #pragma unroll
    for (int off = 1; off < 64; off <<= 1) {
        int o = __shfl_up(pre, off, 64);
        if (lane >= off) pre += o;
    }
    if (lane == 63) wsum[wave] = pre;
    __syncthreads();
    if (t == 0) {
        int r = 0;
        #pragma unroll
        for (int q = 0; q < 8; ++q) { int v = wsum[q]; wsum[q] = r; r += v; }
        stot = r;
    }
    __syncthreads();
    const int tb = wsum[wave] + pre - s;   // exclusive base for bin b4+0

    // write local offsets back (all count reads were 2 barriers ago) and
    // reserve global ranges: 4 INDEPENDENT atomics per thread, ~1450/block
    if (b4 + 0 < N_BINS) {
        hist[b4 + 0]  = tb;
        gbase[b4 + 0] = c0 ? atomicAdd(&cursor[b4 + 0], c0) : 0;
    }
    if (b4 + 1 < N_BINS) {
        hist[b4 + 1]  = tb + c0;
        gbase[b4 + 1] = c1 ? atomicAdd(&cursor[b4 + 1], c1) : 0;
    }
    if (b4 + 2 < N_BINS) {
        hist[b4 + 2]  = tb + c0 + c1;
        gbase[b4 + 2] = c2 ? atomicAdd(&cursor[b4 + 2], c2) : 0;
    }
    if (b4 + 3 < N_BINS) {
        hist[b4 + 3]  = tb + c0 + c1 + c2;
        gbase[b4 + 3] = c3 ? atomicAdd(&cursor[b4 + 3], c3) : 0;
    }
    __syncthreads();

    // scatter to LDS in bin-sorted order
    #pragma unroll
    for (int k = 0; k < 8; ++k)
        if (bn[k] >= 0)
            sorted[hist[bn[k]] + rk[k]] = make_int2(meta[k], wb[k]);
    __syncthreads();

    // grouped write-out: lanes cover consecutive sorted slots
    const int tot = stot;
    #pragma unroll
    for (int k = 0; k < 8; ++k) {
        int i = t + k * 512;
        if (i < tot) {
            int2 q = sorted[i];
            int b = ((unsigned)q.x) >> 21;          // bin (11 bits, unsigned!)
            int r = i - hist[b];                    // rank within (block,bin)
            int g = gbase[b] + r;
            if (g < CAPBIN)
                entries[(size_t)b * CAPBIN + g] = make_int2(q.x & 0x1FFFFF, q.y);
        }
    }
}

// ---------------- gatherB: LDS node sort + register-acc gather ------------
// Entries for bin are dense at [bin*CAPBIN, bin*CAPBIN + cursor[bin]).
__global__ __launch_bounds__(512) void gatherB(
    const unsigned short* __restrict__ ybf, const float* __restrict__ h0,
    const int* __restrict__ cursor, const int2* __restrict__ entries,
    unsigned short* __restrict__ hbf)
{
    __shared__ int2 sorted[CAPBIN];   // 12 KB
    __shared__ int  cnt32[BIN_SZ];
    __shared__ int  offs32[BIN_SZ];

    const int t = threadIdx.x;
    const int bin = blockIdx.x;
    const int node0 = bin * BIN_SZ;
    const int wave = t >> 6, lane = t & 63;

    const int tot = min(cursor[bin], CAPBIN);
    if (t < BIN_SZ) cnt32[t] = 0;
    __syncthreads();

    // pass A: read my <=3 entries (coalesced, dense), rank within dst node
    int2 held[3];
    int  hrank[3], hdloc[3];
    #pragma unroll
    for (int k = 0; k < 3; ++k) {
        hdloc[k] = -1;
        int g = t + k * 512;
        if (g < tot) {
            int2 ep = entries[(size_t)bin * CAPBIN + g];
            int dloc = ep.x >> 16;                  // 5 bits (bin stripped)
            held[k]  = make_int2(ep.x & 0xFFFF, ep.y);
            hdloc[k] = dloc;
            hrank[k] = atomicAdd(&cnt32[dloc], 1);
        }
    }
    __syncthreads();

    // scan cnt32 -> offs32 (wave 0, shfl prefix over 32 lanes)
    if (wave == 0) {
        int v = (lane < BIN_SZ) ? cnt32[lane] : 0;
        int sum = v;
        #pragma unroll
        for (int off = 1; off < BIN_SZ; off <<= 1) {
            int o = __shfl_up(sum, off, 64);
            if (lane >= off) sum += o;
        }
        if (lane < BIN_SZ) offs32[lane] = sum - v;
    }
    __syncthreads();

    // pass B: scatter held entries to node-sorted order
    #pragma unroll
    for (int k = 0; k < 3; ++k)
        if (hdloc[k] >= 0)
            sorted[offs32[hdloc[k]] + hrank[k]] = held[k];
    __syncthreads();

    // per-node gather, register accumulation
    #pragma unroll
    for (int n4 = 0; n4 < 4; ++n4) {
        const int nl = wave * 4 + n4;
        const int node = node0 + nl;
        const int beg = offs32[nl];
        const int c = cnt32[nl];
        float a0 = 0.f, a1 = 0.f;
        int j = 0;
        for (; j + 4 <= c; j += 4) {
            int2 q0 = sorted[beg + j];       // ds_read_b64, broadcast
            int2 q1 = sorted[beg + j + 1];
            int2 q2 = sorted[beg + j + 2];
            int2 q3 = sorted[beg + j + 3];
            unsigned u0 = *(const unsigned*)&ybf[(size_t)q0.x * HID + 2 * lane];
            unsigned u1 = *(const unsigned*)&ybf[(size_t)q1.x * HID + 2 * lane];
            unsigned u2 = *(const unsigned*)&ybf[(size_t)q2.x * HID + 2 * lane];
            unsigned u3 = *(const unsigned*)&ybf[(size_t)q3.x * HID + 2 * lane];
            float w0 = __int_as_float(q0.y), w1 = __int_as_float(q1.y);
            float w2 = __int_as_float(q2.y), w3 = __int_as_float(q3.y);
            a0 += w0 * bflo(u0); a1 += w0 * bfhi(u0);
            a0 += w1 * bflo(u1); a1 += w1 * bfhi(u1);
            a0 += w2 * bflo(u2); a1 += w2 * bfhi(u2);
            a0 += w3 * bflo(u3); a1 += w3 * bfhi(u3);
        }
        for (; j < c; ++j) {
            int2 q = sorted[beg + j];
            unsigned u = *(const unsigned*)&ybf[(size_t)q.x * HID + 2 * lane];
            float wq = __int_as_float(q.y);
            a0 += wq * bflo(u); a1 += wq * bfhi(u);
        }
        if (node < N_NODES) {
            float2 hv = *(const float2*)&h0[(size_t)node * HID + 2 * lane];
            unsigned r = ((unsigned)f2bf(hv.y + a1) << 16)
                       | (unsigned)f2bf(hv.x + a0);
            *(unsigned*)&hbf[(size_t)node * HID + 2 * lane] = r;
        }
    }
}

// ---------------- GEMM1: h0 = x@Wn + (bn+be)  (y-half: ybf = bf16(x@We)) ---
__global__ __launch_bounds__(256) void gemm1(
    const float* __restrict__ x, const unsigned short* __restrict__ Wcat_t,
    const float* __restrict__ bn, const float* __restrict__ be,
    float* __restrict__ h0, unsigned short* __restrict__ ybf)
{
    __shared__ unsigned short As[128][128];  // 32 KB
    __shared__ unsigned short Bs[128][128];  // 32 KB
    const int t = threadIdx.x;
    const int m0 = blockIdx.x * 128;
    const int nhalf = blockIdx.y;            // 0 -> h0, 1 -> ybf
    const int n0r = nhalf * 128;

    const int wave = t >> 6, lane = t & 63;
    const int wm = wave & 1, wn = wave >> 1;
    const int la = lane & 15, kq = lane >> 4;

    f32x4 acc[4][4];
    const f32x4 zero = {0.f, 0.f, 0.f, 0.f};
    #pragma unroll
    for (int i = 0; i < 4; ++i)
        #pragma unroll
        for (int j = 0; j < 4; ++j) acc[i][j] = zero;

    const float4* xg = (const float4*)x;
    const float4* bg = (const float4*)Wcat_t;

    for (int kh = 0; kh < 2; ++kh) {
        if (kh) __syncthreads();
        #pragma unroll
        for (int i = 0; i < 16; ++i) {
            int f4  = t + i * 256;
            int row = f4 >> 5;
            int c4  = f4 & 31;
            int node = m0 + row;
            float4 v = make_float4(0.f, 0.f, 0.f, 0.f);
            if (node < N_NODES) v = xg[(size_t)node * 64 + kh * 32 + c4];
            ushort4 b;
            b.x = f2bf(v.x); b.y = f2bf(v.y); b.z = f2bf(v.z); b.w = f2bf(v.w);
            *(ushort4*)&As[row][c4 * 4] = b;
        }
        #pragma unroll
        for (int i = 0; i < 8; ++i) {
            int f4  = t + i * 256;
            int row = f4 >> 4;
            int c4  = f4 & 15;
            ((float4*)&Bs[0][0])[f4] = bg[(size_t)(n0r + row) * 32 + kh * 16 + c4];
        }
        __syncthreads();

        #pragma unroll
        for (int ks = 0; ks < 4; ++ks) {
            int k = ks * 32 + kq * 8;
            bf16x8 a[4], b[4];
            #pragma unroll
            for (int i = 0; i < 4; ++i)
                a[i] = *(const bf16x8*)&As[wm * 64 + i * 16 + la][k];
            #pragma unroll
            for (int j = 0; j < 4; ++j)
                b[j] = *(const bf16x8*)&Bs[wn * 64 + j * 16 + la][k];
            #pragma unroll
            for (int i = 0; i < 4; ++i)
                #pragma unroll
                for (int j = 0; j < 4; ++j)
                    acc[i][j] = __builtin_amdgcn_mfma_f32_16x16x32_bf16(
                        a[i], b[j], acc[i][j], 0, 0, 0);
        }
    }

    float bias[4];
    if (nhalf == 0) {
        #pragma unroll
        for (int j = 0; j < 4; ++j) {
            int n = wn * 64 + j * 16 + la;
            bias[j] = bn[n] + be[n];
        }
    }
    #pragma unroll
    for (int i = 0; i < 4; ++i) {
        int mbase = m0 + wm * 64 + i * 16 + kq * 4;
        #pragma unroll
        for (int j = 0; j < 4; ++j) {
            int n = wn * 64 + j * 16 + la;
            #pragma unroll
            for (int r = 0; r < 4; ++r) {
                int m = mbase + r;
                if (m < N_NODES) {
                    if (nhalf == 0)
                        h0[(size_t)m * HID + n] = acc[i][j][r] + bias[j];
                    else
                        ybf[(size_t)m * HID + n] = f2bf(acc[i][j][r]);
                }
            }
        }
    }
}

// ---------------- GEMM2: out = hbf@Wm + bm ----------------
__global__ __launch_bounds__(256) void gemm2(
    const unsigned short* __restrict__ hbf, const unsigned short* __restrict__ Wmt,
    const float* __restrict__ bm, float* __restrict__ out)
{
    __shared__ unsigned short As[128][128];
    __shared__ unsigned short Bs[128][128];
    const int t = threadIdx.x;
    const int m0 = blockIdx.x * 128;
    const int n0 = blockIdx.y * 128;

    const float4* ag = (const float4*)hbf;
    #pragma unroll
    for (int i = 0; i < 8; ++i) {
        int f4  = t + i * 256;
        int row = f4 >> 4;
        int node = m0 + row;
        float4 v = make_float4(0.f, 0.f, 0.f, 0.f);
        if (node < N_NODES) v = ag[(size_t)node * 16 + (f4 & 15)];
        ((float4*)&As[0][0])[f4] = v;
    }
    const float4* bg = (const float4*)(Wmt + (size_t)n0 * HID);
    #pragma unroll
    for (int i = 0; i < 8; ++i)
        ((float4*)&Bs[0][0])[t + i * 256] = bg[t + i * 256];
    __syncthreads();

    const int wave = t >> 6, lane = t & 63;
    const int wm = wave & 1, wn = wave >> 1;
    const int la = lane & 15, kq = lane >> 4;

    f32x4 acc[4][4];
    const f32x4 zero = {0.f, 0.f, 0.f, 0.f};
    #pragma unroll
    for (int i = 0; i < 4; ++i)
        #pragma unroll
        for (int j = 0; j < 4; ++j) acc[i][j] = zero;

    #pragma unroll
    for (int ks = 0; ks < 4; ++ks) {
        int k = ks * 32 + kq * 8;
        bf16x8 a[4], b[4];
        #pragma unroll
        for (int i = 0; i < 4; ++i)
            a[i] = *(const bf16x8*)&As[wm * 64 + i * 16 + la][k];
        #pragma unroll
        for (int j = 0; j < 4; ++j)
            b[j] = *(const bf16x8*)&Bs[wn * 64 + j * 16 + la][k];
        #pragma unroll
        for (int i = 0; i < 4; ++i)
            #pragma unroll
            for (int j = 0; j < 4; ++j)
                acc[i][j] = __builtin_amdgcn_mfma_f32_16x16x32_bf16(
                    a[i], b[j], acc[i][j], 0, 0, 0);
    }

    #pragma unroll
    for (int i = 0; i < 4; ++i) {
        int mbase = m0 + wm * 64 + i * 16 + kq * 4;
        #pragma unroll
        for (int j = 0; j < 4; ++j) {
            int n = n0 + wn * 64 + j * 16 + la;
            float b = bm[n];
            #pragma unroll
            for (int r = 0; r < 4; ++r) {
                int m = mbase + r;
                if (m < N_NODES)
                    out[(size_t)m * OUT_FEAT + n] = acc[i][j][r] + b;
            }
        }
    }
}

extern "C" void kernel_launch(void* const* d_in, const int* in_sizes, int n_in,
                              void* d_out, int out_size, void* d_ws, size_t ws_size,
                              hipStream_t stream) {
    const float* x   = (const float*)d_in[0];
    const float* w   = (const float*)d_in[1];
    const int*   src = (const int*)d_in[2];
    const int*   dst = (const int*)d_in[3];
    const float* Wn  = (const float*)d_in[4];
    const float* bn  = (const float*)d_in[5];
    const float* We  = (const float*)d_in[6];
    const float* be  = (const float*)d_in[7];
    const float* Wm  = (const float*)d_in[8];
    const float* bm  = (const float*)d_in[9];
    float* out = (float*)d_out;

    char* p = (char*)d_ws;
    float*          h0      = (float*)p;          p += (size_t)N_NODES * HID * 4;        // 25.6 MB
    unsigned short* ybf     = (unsigned short*)p; p += (size_t)N_NODES * HID * 2;        // 12.8 MB
    unsigned short* hbf     = (unsigned short*)p; p += (size_t)N_NODES * HID * 2;        // 12.8 MB
    int2*           entries = (int2*)p;           p += (size_t)N_BINS * CAPBIN * 8;      // 19.2 MB
    unsigned short* Wcat_t  = (unsigned short*)p; p += (size_t)256 * IN_FEAT * 2;        // 128 KB
    unsigned short* Wmt     = (unsigned short*)p; p += (size_t)OUT_FEAT * HID * 2;       // 64 KB
    int*            cursor  = (int*)p;            p += (size_t)N_BINS * 4;               // 6.3 KB

    const int grid_m = (N_NODES + 127) / 128;   // 391
    dim3 blk(256);

    hipMemsetAsync(cursor, 0, (size_t)N_BINS * 4, stream);
    k0_convert<<<256, blk, 0, stream>>>(Wn, We, Wm, Wcat_t, Wmt);
    binC<<<N_CBLK, dim3(512), 0, stream>>>(src, dst, w, cursor, entries);
    gemm1<<<dim3(grid_m, 2), blk, 0, stream>>>(x, Wcat_t, bn, be, h0, ybf);
    gatherB<<<N_BINS, dim3(512), 0, stream>>>(ybf, h0, cursor, entries, hbf);
    gemm2<<<dim3(grid_m, 2), blk, 0, stream>>>(hbf, Wmt, bm, out);
}

// Round 3
// 268.799 us; speedup vs baseline: 1.2120x; 1.0470x over previous
//
#include <hip/hip_runtime.h>

// SmoothGCN: out = ((x@Wn + bn) + (segsum(x[src]*w, dst)@We + be)) @ Wm + bm
// Refactor: y = x@We; h = x@Wn + bn + be; h[dst] += w_e*y[src]; out = h@Wm + bm
// R9: R8 (global_load_lds variant) failed in-container twice; this round
// keeps the actual theory -- occupancy -- without the builtin. gemm1/gemm2:
// BK=64 K-steps (As/Bs 16KB each, 32KB/block -> 4 blocks/CU at VGPR<=128,
// launch_bounds(256,4)) with reg-staged vectorized loads; LDS XOR-swizzle
// (c8 ^= row&7) on BOTH write and read sides kills the 16-way bank conflict
// (R1: SQ_LDS_BANK_CONFLICT=5.6M in gemm1) down to the b128 8-cycle floor.

constexpr int N_NODES  = 50000;
constexpr int N_EDGES  = 1600000;
constexpr int IN_FEAT  = 256;
constexpr int HID      = 128;
constexpr int OUT_FEAT = 256;

constexpr int BIN_SZ   = 32;                                // nodes per bin
constexpr int N_BINS   = (N_NODES + BIN_SZ - 1) / BIN_SZ;   // 1563
constexpr int CAPBIN   = 1536;   // mean 1024, multinomial max ~1150, P(>1536)~0
constexpr int EPB      = 4096;   // edges per binC block
constexpr int N_CBLK   = (N_EDGES + EPB - 1) / EPB;         // 391

typedef __attribute__((ext_vector_type(8))) short bf16x8;
typedef __attribute__((ext_vector_type(8))) unsigned short u16x8;
typedef __attribute__((ext_vector_type(4))) float f32x4;

static __device__ __forceinline__ unsigned short f2bf(float f) {
    unsigned u = __builtin_bit_cast(unsigned, f);
    u += 0x7FFF + ((u >> 16) & 1);          // round-to-nearest-even
    return (unsigned short)(u >> 16);
}
static __device__ __forceinline__ float bflo(unsigned u) {
    return __builtin_bit_cast(float, u << 16);
}
static __device__ __forceinline__ float bfhi(unsigned u) {
    return __builtin_bit_cast(float, u & 0xFFFF0000u);
}

// ---------------- k0: transpose+convert weights to bf16 ----------------
__global__ __launch_bounds__(256) void k0_convert(
    const float* __restrict__ Wn, const float* __restrict__ We,
    const float* __restrict__ Wm,
    unsigned short* __restrict__ Wcat_t, unsigned short* __restrict__ Wmt)
{
    int n = blockIdx.x;      // 0..255
    int k = threadIdx.x;     // 0..255
    float v = (n < HID) ? Wn[(size_t)k * HID + n] : We[(size_t)k * HID + (n - HID)];
    Wcat_t[(size_t)n * IN_FEAT + k] = f2bf(v);
    if (k < HID) Wmt[(size_t)n * HID + k] = f2bf(Wm[(size_t)k * OUT_FEAT + n]);
}

// ---------------- binC: LDS counting sort of edges into dst bins ----------
__global__ __launch_bounds__(512) void binC(
    const int* __restrict__ src, const int* __restrict__ dst,
    const float* __restrict__ w, int* __restrict__ cursor,
    int2* __restrict__ entries)
{
    __shared__ int  hist[N_BINS];    // counts, then (in place) local excl offsets
    __shared__ int  gbase[N_BINS];   // reserved global base per bin
    __shared__ int  wsum[8];
    __shared__ int  stot;
    __shared__ int2 sorted[EPB];     // 32 KB

    const int t = threadIdx.x;
    const int wave = t >> 6, lane = t & 63;
    const int e0 = blockIdx.x * EPB;

    for (int i = t; i < N_BINS; i += 512) hist[i] = 0;
    __syncthreads();

    // load my 8 edges (coalesced), rank within (block,bin) via LDS atomics
    int meta[8], wb[8], rk[8], bn[8];
    #pragma unroll
    for (int k = 0; k < 8; ++k) {
        int e = e0 + t + k * 512;
        bn[k] = -1;
        if (e < N_EDGES) {
            int d = dst[e];
            int b = d >> 5;
            bn[k]   = b;
            meta[k] = src[e] | ((d & 31) << 16) | (b << 21);  // src<65536 ok
            wb[k]   = __float_as_int(w[e]);
            rk[k]   = atomicAdd(&hist[b], 1);
        }
    }
    __syncthreads();

    // block exclusive scan of hist (4 contiguous bins per thread)
    const int b4 = t * 4;
    int c0 = 0, c1 = 0, c2 = 0, c3 = 0;
    if (b4 + 0 < N_BINS) c0 = hist[b4 + 0];
    if (b4 + 1 < N_BINS) c1 = hist[b4 + 1];
    if (b4 + 2 < N_BINS) c2 = hist[b4 + 2];
    if (b4 + 3 < N_BINS) c3 = hist[b4 + 3];
    const int s = c0 + c1 + c2 + c3;
    int pre = s;
    #pragma unroll
    for (int off = 1; off < 64; off <<= 1) {
        int o = __shfl_up(pre, off, 64);
        if (lane >= off) pre += o;
    }
    if (lane == 63) wsum[wave] = pre;
    __syncthreads();
    if (t == 0) {
        int r = 0;
        #pragma unroll
        for (int q = 0; q < 8; ++q) { int v = wsum[q]; wsum[q] = r; r += v; }
        stot = r;
    }
    __syncthreads();
    const int tb = wsum[wave] + pre - s;   // exclusive base for bin b4+0

    if (b4 + 0 < N_BINS) {
        hist[b4 + 0]  = tb;
        gbase[b4 + 0] = c0 ? atomicAdd(&cursor[b4 + 0], c0) : 0;
    }
    if (b4 + 1 < N_BINS) {
        hist[b4 + 1]  = tb + c0;
        gbase[b4 + 1] = c1 ? atomicAdd(&cursor[b4 + 1], c1) : 0;
    }
    if (b4 + 2 < N_BINS) {
        hist[b4 + 2]  = tb + c0 + c1;
        gbase[b4 + 2] = c2 ? atomicAdd(&cursor[b4 + 2], c2) : 0;
    }
    if (b4 + 3 < N_BINS) {
        hist[b4 + 3]  = tb + c0 + c1 + c2;
        gbase[b4 + 3] = c3 ? atomicAdd(&cursor[b4 + 3], c3) : 0;
    }
    __syncthreads();

    // scatter to LDS in bin-sorted order
    #pragma unroll
    for (int k = 0; k < 8; ++k)
        if (bn[k] >= 0)
            sorted[hist[bn[k]] + rk[k]] = make_int2(meta[k], wb[k]);
    __syncthreads();

    // grouped write-out: lanes cover consecutive sorted slots
    const int tot = stot;
    #pragma unroll
    for (int k = 0; k < 8; ++k) {
        int i = t + k * 512;
        if (i < tot) {
            int2 q = sorted[i];
            int b = ((unsigned)q.x) >> 21;          // bin (11 bits, unsigned!)
            int r = i - hist[b];                    // rank within (block,bin)
            int g = gbase[b] + r;
            if (g < CAPBIN)
                entries[(size_t)b * CAPBIN + g] = make_int2(q.x & 0x1FFFFF, q.y);
        }
    }
}

// ---------------- gatherB: LDS node sort + register-acc gather ------------
__global__ __launch_bounds__(512) void gatherB(
    const unsigned short* __restrict__ ybf, const float* __restrict__ h0,
    const int* __restrict__ cursor, const int2* __restrict__ entries,
    unsigned short* __restrict__ hbf)
{
    __shared__ int2 sorted[CAPBIN];   // 12 KB
    __shared__ int  cnt32[BIN_SZ];
    __shared__ int  offs32[BIN_SZ];

    const int t = threadIdx.x;
    const int bin = blockIdx.x;
    const int node0 = bin * BIN_SZ;
    const int wave = t >> 6, lane = t & 63;

    const int tot = min(cursor[bin], CAPBIN);
    if (t < BIN_SZ) cnt32[t] = 0;
    __syncthreads();

    // pass A: read my <=3 entries (coalesced, dense), rank within dst node
    int2 held[3];
    int  hrank[3], hdloc[3];
    #pragma unroll
    for (int k = 0; k < 3; ++k) {
        hdloc[k] = -1;
        int g = t + k * 512;
        if (g < tot) {
            int2 ep = entries[(size_t)bin * CAPBIN + g];
            int dloc = ep.x >> 16;                  // 5 bits (bin stripped)
            held[k]  = make_int2(ep.x & 0xFFFF, ep.y);
            hdloc[k] = dloc;
            hrank[k] = atomicAdd(&cnt32[dloc], 1);
        }
    }
    __syncthreads();

    // scan cnt32 -> offs32 (wave 0, shfl prefix over 32 lanes)
    if (wave == 0) {
        int v = (lane < BIN_SZ) ? cnt32[lane] : 0;
        int sum = v;
        #pragma unroll
        for (int off = 1; off < BIN_SZ; off <<= 1) {
            int o = __shfl_up(sum, off, 64);
            if (lane >= off) sum += o;
        }
        if (lane < BIN_SZ) offs32[lane] = sum - v;
    }
    __syncthreads();

    // pass B: scatter held entries to node-sorted order
    #pragma unroll
    for (int k = 0; k < 3; ++k)
        if (hdloc[k] >= 0)
            sorted[offs32[hdloc[k]] + hrank[k]] = held[k];
    __syncthreads();

    // per-node gather, register accumulation
    #pragma unroll
    for (int n4 = 0; n4 < 4; ++n4) {
        const int nl = wave * 4 + n4;
        const int node = node0 + nl;
        const int beg = offs32[nl];
        const int c = cnt32[nl];
        float a0 = 0.f, a1 = 0.f;
        int j = 0;
        for (; j + 4 <= c; j += 4) {
            int2 q0 = sorted[beg + j];       // ds_read_b64, broadcast
            int2 q1 = sorted[beg + j + 1];
            int2 q2 = sorted[beg + j + 2];
            int2 q3 = sorted[beg + j + 3];
            unsigned u0 = *(const unsigned*)&ybf[(size_t)q0.x * HID + 2 * lane];
            unsigned u1 = *(const unsigned*)&ybf[(size_t)q1.x * HID + 2 * lane];
            unsigned u2 = *(const unsigned*)&ybf[(size_t)q2.x * HID + 2 * lane];
            unsigned u3 = *(const unsigned*)&ybf[(size_t)q3.x * HID + 2 * lane];
            float w0 = __int_as_float(q0.y), w1 = __int_as_float(q1.y);
            float w2 = __int_as_float(q2.y), w3 = __int_as_float(q3.y);
            a0 += w0 * bflo(u0); a1 += w0 * bfhi(u0);
            a0 += w1 * bflo(u1); a1 += w1 * bfhi(u1);
            a0 += w2 * bflo(u2); a1 += w2 * bfhi(u2);
            a0 += w3 * bflo(u3); a1 += w3 * bfhi(u3);
        }
        for (; j < c; ++j) {
            int2 q = sorted[beg + j];
            unsigned u = *(const unsigned*)&ybf[(size_t)q.x * HID + 2 * lane];
            float wq = __int_as_float(q.y);
            a0 += wq * bflo(u); a1 += wq * bfhi(u);
        }
        if (node < N_NODES) {
            float2 hv = *(const float2*)&h0[(size_t)node * HID + 2 * lane];
            unsigned r = ((unsigned)f2bf(hv.y + a1) << 16)
                       | (unsigned)f2bf(hv.x + a0);
            *(unsigned*)&hbf[(size_t)node * HID + 2 * lane] = r;
        }
    }
}

// ---------------- GEMM1: h0 = x@Wn + (bn+be)  (y-half: ybf = bf16(x@We)) ---
// BK=64: As/Bs 16KB each -> 32KB LDS -> 4 blocks/CU. Reg-staged loads with
// XOR-swizzled 16B-group placement (c8 ^ (row&7)), same XOR on reads.
__global__ __launch_bounds__(256, 4) void gemm1(
    const float* __restrict__ x, const unsigned short* __restrict__ Wcat_t,
    const float* __restrict__ bn, const float* __restrict__ be,
    float* __restrict__ h0, unsigned short* __restrict__ ybf)
{
    __shared__ unsigned short As[128][64];  // 16 KB
    __shared__ unsigned short Bs[128][64];  // 16 KB
    const int t = threadIdx.x;
    const int m0 = blockIdx.x * 128;
    const int nhalf = blockIdx.y;            // 0 -> h0, 1 -> ybf
    const int n0r = nhalf * 128;

    const int wave = t >> 6, lane = t & 63;
    const int wm = wave & 1, wn = wave >> 1;
    const int la = lane & 15, kq = lane >> 4;

    f32x4 acc[4][4];
    const f32x4 zero = {0.f, 0.f, 0.f, 0.f};
    #pragma unroll
    for (int i = 0; i < 4; ++i)
        #pragma unroll
        for (int j = 0; j < 4; ++j) acc[i][j] = zero;

    const float4* xg = (const float4*)x;
    const int srow = t >> 3, sc8 = t & 7;    // staging coords (row, 16B group)

    for (int kt = 0; kt < 4; ++kt) {
        if (kt) __syncthreads();
        // As[128][64] <- bf16(x rows m0.., cols kt*64..+63), swizzled groups
        #pragma unroll
        for (int i = 0; i < 4; ++i) {
            int row = srow + i * 32;
            int node = m0 + row;
            float4 v0 = make_float4(0.f, 0.f, 0.f, 0.f), v1 = v0;
            if (node < N_NODES) {
                v0 = xg[(size_t)node * 64 + kt * 16 + sc8 * 2];
                v1 = xg[(size_t)node * 64 + kt * 16 + sc8 * 2 + 1];
            }
            u16x8 b;
            b[0] = f2bf(v0.x); b[1] = f2bf(v0.y); b[2] = f2bf(v0.z); b[3] = f2bf(v0.w);
            b[4] = f2bf(v1.x); b[5] = f2bf(v1.y); b[6] = f2bf(v1.z); b[7] = f2bf(v1.w);
            *(u16x8*)&As[row][(sc8 ^ (row & 7)) * 8] = b;
        }
        // Bs[128][64] <- Wcat_t rows n0r..n0r+127, cols kt*64..+63
        #pragma unroll
        for (int i = 0; i < 4; ++i) {
            int row = srow + i * 32;
            float4 v = *(const float4*)(
                Wcat_t + (size_t)(n0r + row) * IN_FEAT + kt * 64 + sc8 * 8);
            *(float4*)&Bs[row][(sc8 ^ (row & 7)) * 8] = v;
        }
        __syncthreads();

        #pragma unroll
        for (int ks = 0; ks < 2; ++ks) {
            bf16x8 a[4], b[4];
            #pragma unroll
            for (int i = 0; i < 4; ++i) {
                int row = wm * 64 + i * 16 + la;
                a[i] = *(const bf16x8*)&As[row][((ks * 4 + kq) ^ (row & 7)) * 8];
            }
            #pragma unroll
            for (int j = 0; j < 4; ++j) {
                int row = wn * 64 + j * 16 + la;
                b[j] = *(const bf16x8*)&Bs[row][((ks * 4 + kq) ^ (row & 7)) * 8];
            }
            #pragma unroll
            for (int i = 0; i < 4; ++i)
                #pragma unroll
                for (int j = 0; j < 4; ++j)
                    acc[i][j] = __builtin_amdgcn_mfma_f32_16x16x32_bf16(
                        a[i], b[j], acc[i][j], 0, 0, 0);
        }
    }

    float bias[4];
    if (nhalf == 0) {
        #pragma unroll
        for (int j = 0; j < 4; ++j) {
            int n = wn * 64 + j * 16 + la;
            bias[j] = bn[n] + be[n];
        }
    }
    #pragma unroll
    for (int i = 0; i < 4; ++i) {
        int mbase = m0 + wm * 64 + i * 16 + kq * 4;
        #pragma unroll
        for (int j = 0; j < 4; ++j) {
            int n = wn * 64 + j * 16 + la;
            #pragma unroll
            for (int r = 0; r < 4; ++r) {
                int m = mbase + r;
                if (m < N_NODES) {
                    if (nhalf == 0)
                        h0[(size_t)m * HID + n] = acc[i][j][r] + bias[j];
                    else
                        ybf[(size_t)m * HID + n] = f2bf(acc[i][j][r]);
                }
            }
        }
    }
}

// ---------------- GEMM2: out = hbf@Wm + bm ----------------
// BK=64, both operands bf16, reg-staged float4 loads, same XOR swizzle.
__global__ __launch_bounds__(256, 4) void gemm2(
    const unsigned short* __restrict__ hbf, const unsigned short* __restrict__ Wmt,
    const float* __restrict__ bm, float* __restrict__ out)
{
    __shared__ unsigned short As[128][64];
    __shared__ unsigned short Bs[128][64];
    const int t = threadIdx.x;
    const int m0 = blockIdx.x * 128;
    const int n0 = blockIdx.y * 128;

    const int wave = t >> 6, lane = t & 63;
    const int wm = wave & 1, wn = wave >> 1;
    const int la = lane & 15, kq = lane >> 4;
    const int srow = t >> 3, sc8 = t & 7;

    f32x4 acc[4][4];
    const f32x4 zero = {0.f, 0.f, 0.f, 0.f};
    #pragma unroll
    for (int i = 0; i < 4; ++i)
        #pragma unroll
        for (int j = 0; j < 4; ++j) acc[i][j] = zero;

    for (int kt = 0; kt < 2; ++kt) {
        if (kt) __syncthreads();
        #pragma unroll
        for (int i = 0; i < 4; ++i) {
            int row = srow + i * 32;
            int node = m0 + row;
            if (node >= N_NODES) node = N_NODES - 1;   // dup row; dropped at store
            float4 va = *(const float4*)(hbf + (size_t)node * HID + kt * 64 + sc8 * 8);
            float4 vb = *(const float4*)(Wmt + (size_t)(n0 + row) * HID + kt * 64 + sc8 * 8);
            *(float4*)&As[row][(sc8 ^ (row & 7)) * 8] = va;
            *(float4*)&Bs[row][(sc8 ^ (row & 7)) * 8] = vb;
        }
        __syncthreads();

        #pragma unroll
        for (int ks = 0; ks < 2; ++ks) {
            bf16x8 a[4], b[4];
            #pragma unroll
            for (int i = 0; i < 4; ++i) {
                int row = wm * 64 + i * 16 + la;
                a[i] = *(const bf16x8*)&As[row][((ks * 4 + kq) ^ (row & 7)) * 8];
            }
            #pragma unroll
            for (int j = 0; j < 4; ++j) {
                int row = wn * 64 + j * 16 + la;
                b[j] = *(const bf16x8*)&Bs[row][((ks * 4 + kq) ^ (row & 7)) * 8];
            }
            #pragma unroll
            for (int i = 0; i < 4; ++i)
                #pragma unroll
                for (int j = 0; j < 4; ++j)
                    acc[i][j] = __builtin_amdgcn_mfma_f32_16x16x32_bf16(
                        a[i], b[j], acc[i][j], 0, 0, 0);
        }
    }

    #pragma unroll
    for (int i = 0; i < 4; ++i) {
        int mbase = m0 + wm * 64 + i * 16 + kq * 4;
        #pragma unroll
        for (int j = 0; j < 4; ++j) {
            int n = n0 + wn * 64 + j * 16 + la;
            float b = bm[n];
            #pragma unroll
            for (int r = 0; r < 4; ++r) {
                int m = mbase + r;
                if (m < N_NODES)
                    out[(size_t)m * OUT_FEAT + n] = acc[i][j][r] + b;
            }
        }
    }
}

extern "C" void kernel_launch(void* const* d_in, const int* in_sizes, int n_in,
                              void* d_out, int out_size, void* d_ws, size_t ws_size,
                              hipStream_t stream) {
    const float* x   = (const float*)d_in[0];
    const float* w   = (const float*)d_in[1];
    const int*   src = (const int*)d_in[2];
    const int*   dst = (const int*)d_in[3];
    const float* Wn  = (const float*)d_in[4];
    const float* bn  = (const float*)d_in[5];
    const float* We  = (const float*)d_in[6];
    const float* be  = (const float*)d_in[7];
    const float* Wm  = (const float*)d_in[8];
    const float* bm  = (const float*)d_in[9];
    float* out = (float*)d_out;

    char* p = (char*)d_ws;
    float*          h0      = (float*)p;          p += (size_t)N_NODES * HID * 4;        // 25.6 MB
    unsigned short* ybf     = (unsigned short*)p; p += (size_t)N_NODES * HID * 2;        // 12.8 MB
    unsigned short* hbf     = (unsigned short*)p; p += (size_t)N_NODES * HID * 2;        // 12.8 MB
    int2*           entries = (int2*)p;           p += (size_t)N_BINS * CAPBIN * 8;      // 19.2 MB
    unsigned short* Wcat_t  = (unsigned short*)p; p += (size_t)256 * IN_FEAT * 2;        // 128 KB
    unsigned short* Wmt     = (unsigned short*)p; p += (size_t)OUT_FEAT * HID * 2;       // 64 KB
    int*            cursor  = (int*)p;            p += (size_t)N_BINS * 4;               // 6.3 KB

    const int grid_m = (N_NODES + 127) / 128;   // 391
    dim3 blk(256);

    hipMemsetAsync(cursor, 0, (size_t)N_BINS * 4, stream);
    k0_convert<<<256, blk, 0, stream>>>(Wn, We, Wm, Wcat_t, Wmt);
    binC<<<N_CBLK, dim3(512), 0, stream>>>(src, dst, w, cursor, entries);
    gemm1<<<dim3(grid_m, 2), blk, 0, stream>>>(x, Wcat_t, bn, be, h0, ybf);
    gatherB<<<N_BINS, dim3(512), 0, stream>>>(ybf, h0, cursor, entries, hbf);
    gemm2<<<dim3(grid_m, 2), blk, 0, stream>>>(hbf, Wmt, bm, out);
}

// Round 4
// 250.783 us; speedup vs baseline: 1.2990x; 1.0718x over previous
//
#include <hip/hip_runtime.h>

// SmoothGCN: out = ((x@Wn + bn) + (segsum(x[src]*w, dst)@We + be)) @ Wm + bm
// Refactor: y = x@We; h = x@Wn + bn + be; h[dst] += w_e*y[src]; out = h@Wm + bm
// R10: two theories from R9's small gain: (1) gemm1's 256-thr tile needed
// ~140 VGPR under a 128 cap -> spills; (2) binC (latency-bound, ~41us) sits
// serially before gemm1 (BW/MFMA-bound) despite zero data dependence.
// Fix both at once: fused kernel `fuse1` = binC blocks (0..390) + gemm1
// blocks (391..1172) at 512 threads. gemm1 retiled to 8 waves, wave owns
// 64x32 -> acc[4][2] = 32 acc VGPRs (~100 total, no spill). LDS union
// 45.3KB -> 2 blocks/CU; heterogeneous co-residency overlaps the phases.

constexpr int N_NODES  = 50000;
constexpr int N_EDGES  = 1600000;
constexpr int IN_FEAT  = 256;
constexpr int HID      = 128;
constexpr int OUT_FEAT = 256;

constexpr int BIN_SZ   = 32;                                // nodes per bin
constexpr int N_BINS   = (N_NODES + BIN_SZ - 1) / BIN_SZ;   // 1563
constexpr int CAPBIN   = 1536;   // mean 1024, multinomial max ~1150, P(>1536)~0
constexpr int EPB      = 4096;   // edges per binC block
constexpr int N_CBLK   = (N_EDGES + EPB - 1) / EPB;         // 391
constexpr int GRID_M   = (N_NODES + 127) / 128;             // 391
constexpr int N_G1BLK  = GRID_M * 2;                        // 782

typedef __attribute__((ext_vector_type(8))) short bf16x8;
typedef __attribute__((ext_vector_type(8))) unsigned short u16x8;
typedef __attribute__((ext_vector_type(4))) float f32x4;

static __device__ __forceinline__ unsigned short f2bf(float f) {
    unsigned u = __builtin_bit_cast(unsigned, f);
    u += 0x7FFF + ((u >> 16) & 1);          // round-to-nearest-even
    return (unsigned short)(u >> 16);
}
static __device__ __forceinline__ float bflo(unsigned u) {
    return __builtin_bit_cast(float, u << 16);
}
static __device__ __forceinline__ float bfhi(unsigned u) {
    return __builtin_bit_cast(float, u & 0xFFFF0000u);
}

// ---------------- k0: transpose+convert weights to bf16 ----------------
__global__ __launch_bounds__(256) void k0_convert(
    const float* __restrict__ Wn, const float* __restrict__ We,
    const float* __restrict__ Wm,
    unsigned short* __restrict__ Wcat_t, unsigned short* __restrict__ Wmt)
{
    int n = blockIdx.x;      // 0..255
    int k = threadIdx.x;     // 0..255
    float v = (n < HID) ? Wn[(size_t)k * HID + n] : We[(size_t)k * HID + (n - HID)];
    Wcat_t[(size_t)n * IN_FEAT + k] = f2bf(v);
    if (k < HID) Wmt[(size_t)n * HID + k] = f2bf(Wm[(size_t)k * OUT_FEAT + n]);
}

// ---------------- fuse1: binC (blocks 0..N_CBLK-1) || gemm1 (rest) --------
union SharedU {
    struct {
        int  hist[N_BINS];
        int  gbase[N_BINS];
        int  wsum[8];
        int  stot;
        int2 sorted[EPB];            // 32 KB
    } bc;                            // ~44.3 KB
    struct {
        unsigned short As[128][64];  // 16 KB
        unsigned short Bs[128][64];  // 16 KB
    } g1;
};

__global__ __launch_bounds__(512, 4) void fuse1(
    const int* __restrict__ src, const int* __restrict__ dst,
    const float* __restrict__ w, int* __restrict__ cursor,
    int2* __restrict__ entries,
    const float* __restrict__ x, const unsigned short* __restrict__ Wcat_t,
    const float* __restrict__ bn, const float* __restrict__ be,
    float* __restrict__ h0, unsigned short* __restrict__ ybf)
{
    __shared__ SharedU sh;
    const int t = threadIdx.x;
    const int wave = t >> 6, lane = t & 63;

    if (blockIdx.x < N_CBLK) {
        // ================= binC role (unchanged logic) =================
        const int e0 = blockIdx.x * EPB;

        for (int i = t; i < N_BINS; i += 512) sh.bc.hist[i] = 0;
        __syncthreads();

        int meta[8], wb[8], rk[8], bin[8];
        #pragma unroll
        for (int k = 0; k < 8; ++k) {
            int e = e0 + t + k * 512;
            bin[k] = -1;
            if (e < N_EDGES) {
                int d = dst[e];
                int b = d >> 5;
                bin[k]  = b;
                meta[k] = src[e] | ((d & 31) << 16) | (b << 21);  // src<65536 ok
                wb[k]   = __float_as_int(w[e]);
                rk[k]   = atomicAdd(&sh.bc.hist[b], 1);
            }
        }
        __syncthreads();

        // block exclusive scan of hist (4 contiguous bins per thread)
        const int b4 = t * 4;
        int c0 = 0, c1 = 0, c2 = 0, c3 = 0;
        if (b4 + 0 < N_BINS) c0 = sh.bc.hist[b4 + 0];
        if (b4 + 1 < N_BINS) c1 = sh.bc.hist[b4 + 1];
        if (b4 + 2 < N_BINS) c2 = sh.bc.hist[b4 + 2];
        if (b4 + 3 < N_BINS) c3 = sh.bc.hist[b4 + 3];
        const int s = c0 + c1 + c2 + c3;
        int pre = s;
        #pragma unroll
        for (int off = 1; off < 64; off <<= 1) {
            int o = __shfl_up(pre, off, 64);
            if (lane >= off) pre += o;
        }
        if (lane == 63) sh.bc.wsum[wave] = pre;
        __syncthreads();
        if (t == 0) {
            int r = 0;
            #pragma unroll
            for (int q = 0; q < 8; ++q) { int v = sh.bc.wsum[q]; sh.bc.wsum[q] = r; r += v; }
            sh.bc.stot = r;
        }
        __syncthreads();
        const int tb = sh.bc.wsum[wave] + pre - s;   // exclusive base for bin b4

        if (b4 + 0 < N_BINS) {
            sh.bc.hist[b4 + 0]  = tb;
            sh.bc.gbase[b4 + 0] = c0 ? atomicAdd(&cursor[b4 + 0], c0) : 0;
        }
        if (b4 + 1 < N_BINS) {
            sh.bc.hist[b4 + 1]  = tb + c0;
            sh.bc.gbase[b4 + 1] = c1 ? atomicAdd(&cursor[b4 + 1], c1) : 0;
        }
        if (b4 + 2 < N_BINS) {
            sh.bc.hist[b4 + 2]  = tb + c0 + c1;
            sh.bc.gbase[b4 + 2] = c2 ? atomicAdd(&cursor[b4 + 2], c2) : 0;
        }
        if (b4 + 3 < N_BINS) {
            sh.bc.hist[b4 + 3]  = tb + c0 + c1 + c2;
            sh.bc.gbase[b4 + 3] = c3 ? atomicAdd(&cursor[b4 + 3], c3) : 0;
        }
        __syncthreads();

        // scatter to LDS in bin-sorted order
        #pragma unroll
        for (int k = 0; k < 8; ++k)
            if (bin[k] >= 0)
                sh.bc.sorted[sh.bc.hist[bin[k]] + rk[k]] = make_int2(meta[k], wb[k]);
        __syncthreads();

        // grouped write-out: lanes cover consecutive sorted slots
        const int tot = sh.bc.stot;
        #pragma unroll
        for (int k = 0; k < 8; ++k) {
            int i = t + k * 512;
            if (i < tot) {
                int2 q = sh.bc.sorted[i];
                int b = ((unsigned)q.x) >> 21;          // bin (unsigned shift!)
                int r = i - sh.bc.hist[b];              // rank within (block,bin)
                int g = sh.bc.gbase[b] + r;
                if (g < CAPBIN)
                    entries[(size_t)b * CAPBIN + g] = make_int2(q.x & 0x1FFFFF, q.y);
            }
        }
    } else {
        // ================= gemm1 role: 8 waves, wave owns 64x32 ========
        const int bid2 = blockIdx.x - N_CBLK;
        const int m0 = (bid2 >> 1) * 128;
        const int nhalf = bid2 & 1;              // 0 -> h0, 1 -> ybf
        const int n0r = nhalf * 128;

        const int wm = wave >> 2, wn = wave & 3; // 2 x 4 wave grid
        const int la = lane & 15, kq = lane >> 4;
        const int srow = t >> 3, sc8 = t & 7;    // staging: row 0..63, group 0..7

        f32x4 acc[4][2];
        const f32x4 zero = {0.f, 0.f, 0.f, 0.f};
        #pragma unroll
        for (int i = 0; i < 4; ++i)
            #pragma unroll
            for (int j = 0; j < 2; ++j) acc[i][j] = zero;

        const float4* xg = (const float4*)x;

        for (int kt = 0; kt < 4; ++kt) {
            if (kt) __syncthreads();
            // As[128][64] <- bf16(x rows m0.., cols kt*64..+63), swizzled
            #pragma unroll
            for (int i = 0; i < 2; ++i) {
                int row = srow + i * 64;
                int node = m0 + row;
                float4 v0 = make_float4(0.f, 0.f, 0.f, 0.f), v1 = v0;
                if (node < N_NODES) {
                    v0 = xg[(size_t)node * 64 + kt * 16 + sc8 * 2];
                    v1 = xg[(size_t)node * 64 + kt * 16 + sc8 * 2 + 1];
                }
                u16x8 b;
                b[0] = f2bf(v0.x); b[1] = f2bf(v0.y); b[2] = f2bf(v0.z); b[3] = f2bf(v0.w);
                b[4] = f2bf(v1.x); b[5] = f2bf(v1.y); b[6] = f2bf(v1.z); b[7] = f2bf(v1.w);
                *(u16x8*)&sh.g1.As[row][(sc8 ^ (row & 7)) * 8] = b;
            }
            // Bs[128][64] <- Wcat_t rows n0r..n0r+127, cols kt*64..+63
            #pragma unroll
            for (int i = 0; i < 2; ++i) {
                int row = srow + i * 64;
                float4 v = *(const float4*)(
                    Wcat_t + (size_t)(n0r + row) * IN_FEAT + kt * 64 + sc8 * 8);
                *(float4*)&sh.g1.Bs[row][(sc8 ^ (row & 7)) * 8] = v;
            }
            __syncthreads();

            #pragma unroll
            for (int ks = 0; ks < 2; ++ks) {
                bf16x8 a[4], b[2];
                #pragma unroll
                for (int i = 0; i < 4; ++i) {
                    int row = wm * 64 + i * 16 + la;
                    a[i] = *(const bf16x8*)&sh.g1.As[row][((ks * 4 + kq) ^ (row & 7)) * 8];
                }
                #pragma unroll
                for (int j = 0; j < 2; ++j) {
                    int row = wn * 32 + j * 16 + la;
                    b[j] = *(const bf16x8*)&sh.g1.Bs[row][((ks * 4 + kq) ^ (row & 7)) * 8];
                }
                #pragma unroll
                for (int i = 0; i < 4; ++i)
                    #pragma unroll
                    for (int j = 0; j < 2; ++j)
                        acc[i][j] = __builtin_amdgcn_mfma_f32_16x16x32_bf16(
                            a[i], b[j], acc[i][j], 0, 0, 0);
            }
        }

        float bias[2];
        if (nhalf == 0) {
            #pragma unroll
            for (int j = 0; j < 2; ++j) {
                int n = wn * 32 + j * 16 + la;
                bias[j] = bn[n] + be[n];
            }
        }
        #pragma unroll
        for (int i = 0; i < 4; ++i) {
            int mbase = m0 + wm * 64 + i * 16 + kq * 4;
            #pragma unroll
            for (int j = 0; j < 2; ++j) {
                int n = wn * 32 + j * 16 + la;
                #pragma unroll
                for (int r = 0; r < 4; ++r) {
                    int m = mbase + r;
                    if (m < N_NODES) {
                        if (nhalf == 0)
                            h0[(size_t)m * HID + n] = acc[i][j][r] + bias[j];
                        else
                            ybf[(size_t)m * HID + n] = f2bf(acc[i][j][r]);
                    }
                }
            }
        }
    }
}

// ---------------- gatherB: LDS node sort + register-acc gather ------------
__global__ __launch_bounds__(512) void gatherB(
    const unsigned short* __restrict__ ybf, const float* __restrict__ h0,
    const int* __restrict__ cursor, const int2* __restrict__ entries,
    unsigned short* __restrict__ hbf)
{
    __shared__ int2 sorted[CAPBIN];   // 12 KB
    __shared__ int  cnt32[BIN_SZ];
    __shared__ int  offs32[BIN_SZ];

    const int t = threadIdx.x;
    const int bin = blockIdx.x;
    const int node0 = bin * BIN_SZ;
    const int wave = t >> 6, lane = t & 63;

    const int tot = min(cursor[bin], CAPBIN);
    if (t < BIN_SZ) cnt32[t] = 0;
    __syncthreads();

    // pass A: read my <=3 entries (coalesced, dense), rank within dst node
    int2 held[3];
    int  hrank[3], hdloc[3];
    #pragma unroll
    for (int k = 0; k < 3; ++k) {
        hdloc[k] = -1;
        int g = t + k * 512;
        if (g < tot) {
            int2 ep = entries[(size_t)bin * CAPBIN + g];
            int dloc = ep.x >> 16;                  // 5 bits (bin stripped)
            held[k]  = make_int2(ep.x & 0xFFFF, ep.y);
            hdloc[k] = dloc;
            hrank[k] = atomicAdd(&cnt32[dloc], 1);
        }
    }
    __syncthreads();

    // scan cnt32 -> offs32 (wave 0, shfl prefix over 32 lanes)
    if (wave == 0) {
        int v = (lane < BIN_SZ) ? cnt32[lane] : 0;
        int sum = v;
        #pragma unroll
        for (int off = 1; off < BIN_SZ; off <<= 1) {
            int o = __shfl_up(sum, off, 64);
            if (lane >= off) sum += o;
        }
        if (lane < BIN_SZ) offs32[lane] = sum - v;
    }
    __syncthreads();

    // pass B: scatter held entries to node-sorted order
    #pragma unroll
    for (int k = 0; k < 3; ++k)
        if (hdloc[k] >= 0)
            sorted[offs32[hdloc[k]] + hrank[k]] = held[k];
    __syncthreads();

    // per-node gather, register accumulation
    #pragma unroll
    for (int n4 = 0; n4 < 4; ++n4) {
        const int nl = wave * 4 + n4;
        const int node = node0 + nl;
        const int beg = offs32[nl];
        const int c = cnt32[nl];
        float a0 = 0.f, a1 = 0.f;
        int j = 0;
        for (; j + 4 <= c; j += 4) {
            int2 q0 = sorted[beg + j];       // ds_read_b64, broadcast
            int2 q1 = sorted[beg + j + 1];
            int2 q2 = sorted[beg + j + 2];
            int2 q3 = sorted[beg + j + 3];
            unsigned u0 = *(const unsigned*)&ybf[(size_t)q0.x * HID + 2 * lane];
            unsigned u1 = *(const unsigned*)&ybf[(size_t)q1.x * HID + 2 * lane];
            unsigned u2 = *(const unsigned*)&ybf[(size_t)q2.x * HID + 2 * lane];
            unsigned u3 = *(const unsigned*)&ybf[(size_t)q3.x * HID + 2 * lane];
            float w0 = __int_as_float(q0.y), w1 = __int_as_float(q1.y);
            float w2 = __int_as_float(q2.y), w3 = __int_as_float(q3.y);
            a0 += w0 * bflo(u0); a1 += w0 * bfhi(u0);
            a0 += w1 * bflo(u1); a1 += w1 * bfhi(u1);
            a0 += w2 * bflo(u2); a1 += w2 * bfhi(u2);
            a0 += w3 * bflo(u3); a1 += w3 * bfhi(u3);
        }
        for (; j < c; ++j) {
            int2 q = sorted[beg + j];
            unsigned u = *(const unsigned*)&ybf[(size_t)q.x * HID + 2 * lane];
            float wq = __int_as_float(q.y);
            a0 += wq * bflo(u); a1 += wq * bfhi(u);
        }
        if (node < N_NODES) {
            float2 hv = *(const float2*)&h0[(size_t)node * HID + 2 * lane];
            unsigned r = ((unsigned)f2bf(hv.y + a1) << 16)
                       | (unsigned)f2bf(hv.x + a0);
            *(unsigned*)&hbf[(size_t)node * HID + 2 * lane] = r;
        }
    }
}

// ---------------- GEMM2: out = hbf@Wm + bm ----------------
// BK=64, both operands bf16, reg-staged float4 loads, XOR swizzle.
__global__ __launch_bounds__(256, 4) void gemm2(
    const unsigned short* __restrict__ hbf, const unsigned short* __restrict__ Wmt,
    const float* __restrict__ bm, float* __restrict__ out)
{
    __shared__ unsigned short As[128][64];
    __shared__ unsigned short Bs[128][64];
    const int t = threadIdx.x;
    const int m0 = blockIdx.x * 128;
    const int n0 = blockIdx.y * 128;

    const int wave = t >> 6, lane = t & 63;
    const int wm = wave & 1, wn = wave >> 1;
    const int la = lane & 15, kq = lane >> 4;
    const int srow = t >> 3, sc8 = t & 7;

    f32x4 acc[4][4];
    const f32x4 zero = {0.f, 0.f, 0.f, 0.f};
    #pragma unroll
    for (int i = 0; i < 4; ++i)
        #pragma unroll
        for (int j = 0; j < 4; ++j) acc[i][j] = zero;

    for (int kt = 0; kt < 2; ++kt) {
        if (kt) __syncthreads();
        #pragma unroll
        for (int i = 0; i < 4; ++i) {
            int row = srow + i * 32;
            int node = m0 + row;
            if (node >= N_NODES) node = N_NODES - 1;   // dup row; dropped at store
            float4 va = *(const float4*)(hbf + (size_t)node * HID + kt * 64 + sc8 * 8);
            float4 vb = *(const float4*)(Wmt + (size_t)(n0 + row) * HID + kt * 64 + sc8 * 8);
            *(float4*)&As[row][(sc8 ^ (row & 7)) * 8] = va;
            *(float4*)&Bs[row][(sc8 ^ (row & 7)) * 8] = vb;
        }
        __syncthreads();

        #pragma unroll
        for (int ks = 0; ks < 2; ++ks) {
            bf16x8 a[4], b[4];
            #pragma unroll
            for (int i = 0; i < 4; ++i) {
                int row = wm * 64 + i * 16 + la;
                a[i] = *(const bf16x8*)&As[row][((ks * 4 + kq) ^ (row & 7)) * 8];
            }
            #pragma unroll
            for (int j = 0; j < 4; ++j) {
                int row = wn * 64 + j * 16 + la;
                b[j] = *(const bf16x8*)&Bs[row][((ks * 4 + kq) ^ (row & 7)) * 8];
            }
            #pragma unroll
            for (int i = 0; i < 4; ++i)
                #pragma unroll
                for (int j = 0; j < 4; ++j)
                    acc[i][j] = __builtin_amdgcn_mfma_f32_16x16x32_bf16(
                        a[i], b[j], acc[i][j], 0, 0, 0);
        }
    }

    #pragma unroll
    for (int i = 0; i < 4; ++i) {
        int mbase = m0 + wm * 64 + i * 16 + kq * 4;
        #pragma unroll
        for (int j = 0; j < 4; ++j) {
            int n = n0 + wn * 64 + j * 16 + la;
            float b = bm[n];
            #pragma unroll
            for (int r = 0; r < 4; ++r) {
                int m = mbase + r;
                if (m < N_NODES)
                    out[(size_t)m * OUT_FEAT + n] = acc[i][j][r] + b;
            }
        }
    }
}

extern "C" void kernel_launch(void* const* d_in, const int* in_sizes, int n_in,
                              void* d_out, int out_size, void* d_ws, size_t ws_size,
                              hipStream_t stream) {
    const float* x   = (const float*)d_in[0];
    const float* w   = (const float*)d_in[1];
    const int*   src = (const int*)d_in[2];
    const int*   dst = (const int*)d_in[3];
    const float* Wn  = (const float*)d_in[4];
    const float* bn  = (const float*)d_in[5];
    const float* We  = (const float*)d_in[6];
    const float* be  = (const float*)d_in[7];
    const float* Wm  = (const float*)d_in[8];
    const float* bm  = (const float*)d_in[9];
    float* out = (float*)d_out;

    char* p = (char*)d_ws;
    float*          h0      = (float*)p;          p += (size_t)N_NODES * HID * 4;        // 25.6 MB
    unsigned short* ybf     = (unsigned short*)p; p += (size_t)N_NODES * HID * 2;        // 12.8 MB
    unsigned short* hbf     = (unsigned short*)p; p += (size_t)N_NODES * HID * 2;        // 12.8 MB
    int2*           entries = (int2*)p;           p += (size_t)N_BINS * CAPBIN * 8;      // 19.2 MB
    unsigned short* Wcat_t  = (unsigned short*)p; p += (size_t)256 * IN_FEAT * 2;        // 128 KB
    unsigned short* Wmt     = (unsigned short*)p; p += (size_t)OUT_FEAT * HID * 2;       // 64 KB
    int*            cursor  = (int*)p;            p += (size_t)N_BINS * 4;               // 6.3 KB

    dim3 blk(256);

    hipMemsetAsync(cursor, 0, (size_t)N_BINS * 4, stream);
    k0_convert<<<256, blk, 0, stream>>>(Wn, We, Wm, Wcat_t, Wmt);
    fuse1<<<N_CBLK + N_G1BLK, dim3(512), 0, stream>>>(
        src, dst, w, cursor, entries, x, Wcat_t, bn, be, h0, ybf);
    gatherB<<<N_BINS, dim3(512), 0, stream>>>(ybf, h0, cursor, entries, hbf);
    gemm2<<<dim3(GRID_M, 2), blk, 0, stream>>>(hbf, Wmt, bm, out);
}